// Round 7
// baseline (848.584 us; speedup 1.0000x reference)
//
#include <hip/hip_runtime.h>
#include <stdint.h>

// GateRow: out[b,g] = gates[g, 2*x[b,c0[g]] + x[b,c1[g]]]
// B=16384, N_IN=8192, N_GATES=8192. Harness canonicalizes bool -> int32
// (confirmed r4/r5). Output int32 0/1: 537 MB writes; x int32: 537 MB reads.
// dur_us decomposition (r5/r6): ~600 us fixed harness resets + gate_main
// ~230 us (floor ~170-200). Round 7: single kernel — meta computed inline
// per block from L2-resident gates/choices (drops pack_meta launch + gap).

static constexpr int BATCH  = 16384;
static constexpr int N_IN   = 8192;
static constexpr int NG     = 8192;
static constexpr int ROWS   = 8;     // batch rows bit-packed per block
static constexpr int BLK    = 256;
static constexpr int GPT    = 4;     // gates per thread per group (dwordx4 store)
static constexpr int NGROUP = NG / (BLK * GPT);   // 8

typedef uint32_t u32x4 __attribute__((ext_vector_type(4)));
typedef int      i32x2 __attribute__((ext_vector_type(2)));

// int32-canonicalized bools => every 32-bit word is 0 or 1.
// Byte-bools => upper-byte bits set w.p. 7/8 per word.
// Ballot over 64 lanes x 4 words => wrong verdict w.p. ~2^-768. Wave-uniform.
__device__ __forceinline__ bool wave_detect_i32(u32x4 w) {
    return __ballot((((w.x | w.y | w.z | w.w) & ~1u) == 0u)) == ~0ULL;
}

__global__ __launch_bounds__(BLK) void gate_main(
        const void*     __restrict__ xv,
        const int*      __restrict__ choices,
        const void*     __restrict__ gates_,
        uint32_t*       __restrict__ out) {
    // xp[c] bit r == x[b0+r][c]  (8 rows bit-packed per byte)
    __shared__ uint8_t xp[N_IN];
    const int  t  = threadIdx.x;
    const long b0 = (long)blockIdx.x * ROWS;

    // Detect x dtype from the first 8.4 MB (in-bounds under BOTH layouts:
    // byte-mode buffer would be 134 MB). One coalesced 16B load per thread.
    // NOTE: must stay a prefix read — staging addresses for the wrong layout
    // would be out of bounds, so detection gates which addresses are formed.
    const bool xi32 = wave_detect_i32(
        ((const u32x4*)xv)[blockIdx.x * BLK + t]);

    // ---- Stage: load 8 rows of x, bit-pack into LDS bytes ------------------
    if (xi32) {
        const uint32_t* x = (const uint32_t*)xv;
        uint32_t* dst = (uint32_t*)xp;           // 4 packed bytes per store
        #pragma unroll
        for (int i = 0; i < N_IN / 4 / BLK; ++i) {   // 8 iterations
            const int o = t + i * BLK;                // 4-column group index
            uint32_t pb = 0;
            #pragma unroll
            for (int r = 0; r < ROWS; ++r) {
                const u32x4* src = (const u32x4*)(x + (b0 + r) * (long)N_IN) + o;
                u32x4 v = __builtin_nontemporal_load(src);
                pb |= (v.x << r) | (v.y << (r + 8))
                    | (v.z << (r + 16)) | (v.w << (r + 24));
            }
            dst[o] = pb;
        }
    } else {
        const u32x4* xr  = (const u32x4*)((const uint8_t*)xv + b0 * N_IN);
        u32x4*       dst = (u32x4*)xp;
        #pragma unroll
        for (int i = 0; i < N_IN / 16 / BLK; ++i) {  // 2 iterations
            const int o = t + i * BLK;                // 16-column group index
            u32x4 p = (u32x4){0u, 0u, 0u, 0u};
            #pragma unroll
            for (int r = 0; r < ROWS; ++r) {
                // bytes are 0/1 -> <<r stays within each byte lane (no carry)
                u32x4 v = __builtin_nontemporal_load(
                    &xr[(size_t)r * (N_IN / 16) + o]);
                p.x |= v.x << r;  p.y |= v.y << r;
                p.z |= v.z << r;  p.w |= v.w << r;
            }
            dst[o] = p;
        }
    }
    __syncthreads();

    // Detect gates dtype from first 4 KB (byte-mode gates buffer is 32 KB,
    // i32-mode 128 KB: safe prefix under both layouts).
    const bool gi32 = wave_detect_i32(((const u32x4*)gates_)[t]);

    // ---- Gate loop: 4 gates/thread/group, 8 rows each ----------------------
    // Meta computed inline: choices (64 KB) + gates (128 KB) are L2-resident
    // after first touch; these loads hide under the HBM store stream.
    #pragma unroll
    for (int k = 0; k < NGROUP; ++k) {
        const int gbase = k * BLK * GPT + t * GPT;

        uint32_t mm[GPT];
        #pragma unroll
        for (int j = 0; j < GPT; ++j) {
            const int g = gbase + j;
            i32x2 c = ((const i32x2*)choices)[g];
            uint32_t tt;
            if (gi32) {
                u32x4 gw = ((const u32x4*)gates_)[g];    // gates[4g..4g+3] i32
                tt = (gw.x & 1u) | ((gw.y & 1u) << 1)
                   | ((gw.z & 1u) << 2) | ((gw.w & 1u) << 3);
            } else {
                uint32_t gw = ((const uint32_t*)gates_)[g];  // 4 byte-bools
                tt = ((gw & 0x01010101u) * 0x01020408u) >> 24;
            }
            mm[j] = (uint32_t)c.x | ((uint32_t)c.y << 13) | (tt << 26);
        }

        uint32_t res[ROWS][GPT];
        #pragma unroll
        for (int j = 0; j < GPT; ++j) {
            const uint32_t mv = mm[j];
            const uint32_t v0 = xp[mv & 8191u];           // 8 rows' chosen0 bits
            const uint32_t v1 = xp[(mv >> 13) & 8191u];   // 8 rows' chosen1 bits
            const uint32_t tt = mv >> 26;
            #pragma unroll
            for (int r = 0; r < ROWS; ++r) {
                const uint32_t idx = (((v0 >> r) & 1u) << 1) | ((v1 >> r) & 1u);
                res[r][j] = (tt >> idx) & 1u;             // int32 0/1 output
            }
        }

        #pragma unroll
        for (int r = 0; r < ROWS; ++r) {
            u32x4 v = { res[r][0], res[r][1], res[r][2], res[r][3] };
            u32x4* dst = (u32x4*)(out + (b0 + r) * (long)NG + gbase);
            __builtin_nontemporal_store(v, dst);   // streaming: out > L3
        }
    }
}

extern "C" void kernel_launch(void* const* d_in, const int* in_sizes, int n_in,
                              void* d_out, int out_size, void* d_ws, size_t ws_size,
                              hipStream_t stream) {
    const void* x       = d_in[0];
    const void* gates   = d_in[1];
    const int*  choices = (const int*)d_in[2];
    uint32_t*   out     = (uint32_t*)d_out;
    (void)d_ws; (void)ws_size;

    gate_main<<<BATCH / ROWS, BLK, 0, stream>>>(x, choices, gates, out);
}

// Round 9
// 817.266 us; speedup vs baseline: 1.0383x; 1.0383x over previous
//
#include <hip/hip_runtime.h>
#include <stdint.h>

// GateRow: out[b,g] = gates[g, 2*x[b,c0[g]] + x[b,c1[g]]]
// B=16384, N_IN=8192, N_GATES=8192. bool->int32 canonicalized (r4/r5).
// dur_us = ~600 us fixed harness resets + gate_main (~230 us, floor ~170).
// Round 8/9: r6 structure (pack_meta + mq preload, measured best 829.7)
// + two-half row pipeline: stage B overlaps compute/store A, so the
// block sustains mixed read+write streams instead of alternating phases.

static constexpr int BATCH  = 16384;
static constexpr int N_IN   = 8192;
static constexpr int NG     = 8192;
static constexpr int ROWS   = 8;     // batch rows per block
static constexpr int HALF   = 4;     // rows per pipeline half
static constexpr int BLK    = 256;
static constexpr int GPT    = 4;     // gates per thread per group (dwordx4 store)
static constexpr int NGROUP = NG / (BLK * GPT);   // 8

typedef uint32_t u32x4 __attribute__((ext_vector_type(4)));
typedef int      i32x2 __attribute__((ext_vector_type(2)));

// int32-canonicalized bools => every 32-bit word is 0 or 1.
// Ballot over 64 lanes x 4 words => wrong verdict w.p. ~2^-768. Wave-uniform.
__device__ __forceinline__ bool wave_detect_i32(u32x4 w) {
    return __ballot((((w.x | w.y | w.z | w.w) & ~1u) == 0u)) == ~0ULL;
}

// ---- Pack per-gate metadata: c0 | c1<<13 | truthtable<<26 ------------------
__global__ __launch_bounds__(BLK) void pack_meta(
        const int* __restrict__ choices,
        const void* __restrict__ gates_,
        uint32_t* __restrict__ meta) {
    const int g = blockIdx.x * BLK + threadIdx.x;   // 32 blocks x 256
    const bool i32 = wave_detect_i32(((const u32x4*)gates_)[g & 2047]);
    i32x2 c = ((const i32x2*)choices)[g];
    uint32_t tt;
    if (i32) {
        u32x4 gw = ((const u32x4*)gates_)[g];       // gates[4g..4g+3] as int32
        tt = (gw.x & 1u) | ((gw.y & 1u) << 1)
           | ((gw.z & 1u) << 2) | ((gw.w & 1u) << 3);
    } else {
        uint32_t gw = ((const uint32_t*)gates_)[g]; // 4 byte-bools
        tt = ((gw & 0x01010101u) * 0x01020408u) >> 24;
    }
    meta[g] = (uint32_t)c.x | ((uint32_t)c.y << 13) | (tt << 26);
}

template <bool PACKED>
__global__ __launch_bounds__(BLK) void gate_main(
        const void*     __restrict__ xv,
        const uint32_t* __restrict__ meta,
        const int*      __restrict__ choices,
        const void*     __restrict__ gates_,
        uint32_t*       __restrict__ out) {
    // xp[h][c] bit r == x[b0 + h*4 + r][c]  (4 rows bit-packed per byte half)
    __shared__ uint8_t xp[2][N_IN];
    const int  t  = threadIdx.x;
    const long b0 = (long)blockIdx.x * ROWS;

    // Detect x dtype from the first 8.4 MB prefix (in-bounds under BOTH
    // layouts; byte-mode buffer would be 134 MB). One 16B load per thread.
    const bool xi32 = wave_detect_i32(
        ((const u32x4*)xv)[blockIdx.x * BLK + t]);

    // ---- Meta preload: 8 independent coalesced loads, issued first ---------
    u32x4 mq[NGROUP];
    if (PACKED) {
        #pragma unroll
        for (int k = 0; k < NGROUP; ++k)
            mq[k] = ((const u32x4*)meta)[k * BLK + t];
    } else {
        const bool gi32 = wave_detect_i32(((const u32x4*)gates_)[t]);
        #pragma unroll
        for (int k = 0; k < NGROUP; ++k) {
            #pragma unroll
            for (int j = 0; j < GPT; ++j) {
                const int g = k * BLK * GPT + t * GPT + j;
                i32x2 c = ((const i32x2*)choices)[g];
                uint32_t tt;
                if (gi32) {
                    u32x4 gw = ((const u32x4*)gates_)[g];
                    tt = (gw.x & 1u) | ((gw.y & 1u) << 1)
                       | ((gw.z & 1u) << 2) | ((gw.w & 1u) << 3);
                } else {
                    uint32_t gw = ((const uint32_t*)gates_)[g];
                    tt = ((gw & 0x01010101u) * 0x01020408u) >> 24;
                }
                mq[k][j] = (uint32_t)c.x | ((uint32_t)c.y << 13) | (tt << 26);
            }
        }
    }

    // ---- Stage one half (4 rows) of x into LDS, bits 0..3 per byte ---------
    auto stage = [&](int h) {
        const long rb = b0 + h * HALF;
        if (xi32) {
            const uint32_t* x = (const uint32_t*)xv;
            uint32_t* dst = (uint32_t*)xp[h];    // 4 packed bytes per store
            #pragma unroll
            for (int i = 0; i < N_IN / 4 / BLK; ++i) {   // 8 iterations
                const int o = t + i * BLK;
                uint32_t pb = 0;
                #pragma unroll
                for (int r = 0; r < HALF; ++r) {
                    const u32x4* src =
                        (const u32x4*)(x + (rb + r) * (long)N_IN) + o;
                    u32x4 v = __builtin_nontemporal_load(src);
                    pb |= (v.x << r) | (v.y << (r + 8))
                        | (v.z << (r + 16)) | (v.w << (r + 24));
                }
                dst[o] = pb;
            }
        } else {
            const u32x4* xr =
                (const u32x4*)((const uint8_t*)xv + rb * N_IN);
            u32x4* dst = (u32x4*)xp[h];
            #pragma unroll
            for (int i = 0; i < N_IN / 16 / BLK; ++i) {  // 2 iterations
                const int o = t + i * BLK;
                u32x4 p = (u32x4){0u, 0u, 0u, 0u};
                #pragma unroll
                for (int r = 0; r < HALF; ++r) {
                    // bytes are 0/1 -> <<r stays within each byte lane
                    u32x4 v = __builtin_nontemporal_load(
                        &xr[(size_t)r * (N_IN / 16) + o]);
                    p.x |= v.x << r;  p.y |= v.y << r;
                    p.z |= v.z << r;  p.w |= v.w << r;
                }
                dst[o] = p;
            }
        }
    };

    // ---- Compute + store one half (4 rows x all gates) ---------------------
    auto compute_store = [&](int h) {
        const long rb = b0 + h * HALF;
        #pragma unroll
        for (int k = 0; k < NGROUP; ++k) {
            const int gbase = k * BLK * GPT + t * GPT;
            uint32_t res[HALF][GPT];
            #pragma unroll
            for (int j = 0; j < GPT; ++j) {
                const uint32_t mv = mq[k][j];
                const uint32_t v0 = xp[h][mv & 8191u];
                const uint32_t v1 = xp[h][(mv >> 13) & 8191u];
                const uint32_t tt = mv >> 26;
                #pragma unroll
                for (int r = 0; r < HALF; ++r) {
                    const uint32_t idx =
                        (((v0 >> r) & 1u) << 1) | ((v1 >> r) & 1u);
                    res[r][j] = (tt >> idx) & 1u;    // int32 0/1 output
                }
            }
            #pragma unroll
            for (int r = 0; r < HALF; ++r) {
                u32x4 v = { res[r][0], res[r][1], res[r][2], res[r][3] };
                u32x4* dst = (u32x4*)(out + (rb + r) * (long)NG + gbase);
                __builtin_nontemporal_store(v, dst);  // streaming: out > L3
            }
        }
    };

    // ---- Two-half pipeline -------------------------------------------------
    stage(0);
    __syncthreads();
    stage(1);            // issued before compute A: read stream overlaps
    compute_store(0);    // ... compute + write stream of half A
    __syncthreads();
    compute_store(1);
}

extern "C" void kernel_launch(void* const* d_in, const int* in_sizes, int n_in,
                              void* d_out, int out_size, void* d_ws, size_t ws_size,
                              hipStream_t stream) {
    const void* x       = d_in[0];
    const void* gates   = d_in[1];
    const int*  choices = (const int*)d_in[2];
    uint32_t*   out     = (uint32_t*)d_out;

    if (ws_size >= NG * sizeof(uint32_t)) {
        uint32_t* meta = (uint32_t*)d_ws;
        pack_meta<<<NG / BLK, BLK, 0, stream>>>(choices, gates, meta);
        gate_main<true><<<BATCH / ROWS, BLK, 0, stream>>>(
            x, meta, choices, gates, out);
    } else {
        gate_main<false><<<BATCH / ROWS, BLK, 0, stream>>>(
            x, nullptr, choices, gates, out);
    }
}